// Round 14
// baseline (635.864 us; speedup 1.0000x reference)
//
#include <hip/hip_runtime.h>
#include <math.h>

#define NNODE 100000
#define NEDGE 600000
#define DIM 128
#define HID 256
#define NLAYERS 2
#define PROJ_BLOCKS 1563   // ceil(NNODE/64)

typedef short bf16x8 __attribute__((ext_vector_type(8)));
typedef short bf16x4 __attribute__((ext_vector_type(4)));
typedef float f32x4 __attribute__((ext_vector_type(4)));
typedef float f32x2 __attribute__((ext_vector_type(2)));

#define WK 136    // proj weight LD (k=128 + pad)
#define WLD 264   // node weight / LDS tile LD (k=256 + pad)
#define LUTN 2048 // entries per table, domain [-8,8), step 1/128

__device__ __forceinline__ short f2bf(float x) {
    union { float f; unsigned u; } v; v.f = x;
    unsigned r = v.u + 0x7FFFu + ((v.u >> 16) & 1u);
    return (short)(r >> 16);
}
__device__ __forceinline__ float bf2f(short s) {
    union { unsigned u; float f; } v; v.u = ((unsigned)(unsigned short)s) << 16;
    return v.f;
}
// fast gelu (sigmoid approx) for node MLP: x * sigmoid(1.702 x)
__device__ __forceinline__ float gelu_fast(float x) {
    float e = exp2f(-2.4554673f * x);           // exp(-1.702x)
    return x * __builtin_amdgcn_rcpf(1.0f + e);
}
// LDS LUT lookup: value at nearest grid point of [-8,8) step 1/128
__device__ __forceinline__ float lut_look(const float* __restrict__ lut, float x) {
    float t = fmaf(x, 128.f, 1024.5f);          // +0.5 -> round to nearest entry
    t = fminf(fmaxf(t, 0.f), 2047.f);
    return lut[(int)t];
}

// ---------------- prep: weights -> bf16 transposed + permuted edge vectors + h0->bf16/fp8 + LUTs + deg hist ----------------
__global__ void prep_weights(const float* __restrict__ ew1,   // [L][257][256]
                             const float* __restrict__ eb1,   // [L][256]
                             const float* __restrict__ ew2,   // [L][256][1]
                             const float* __restrict__ nw1,   // [L][256][256]
                             const float* __restrict__ nw2,   // [L][256][128]
                             const float* __restrict__ h0,    // [N][128] f32
                             const int* __restrict__ ei,      // [E][2]
                             short* __restrict__ pW,          // [L][512][WK]
                             short* __restrict__ nW1T,        // [L][256][WLD]
                             short* __restrict__ nW2T,        // [L][128][WLD]
                             float* __restrict__ w1a_p,       // [L][256] permuted
                             float* __restrict__ b1_p,        // [L][256] permuted
                             float* __restrict__ w2_p,        // [L][256] permuted
                             short* __restrict__ hb,          // [N][128] bf16
                             unsigned char* __restrict__ h8,  // [N][128] fp8 e4m3
                             float* __restrict__ luts,        // [2*LUTN]: gelu | sigmoid
                             int* __restrict__ deg)
{
    int idx = blockIdx.x * 256 + threadIdx.x;
    const int SZ1 = NLAYERS * 512 * 128;
    const int SZ2 = NLAYERS * 256 * 256;
    const int SZ3 = NLAYERS * 128 * 256;
    const int SZ4 = NLAYERS * 256;
    const int SZH = NNODE * DIM / 8;
    if (idx < SZ1) {
        int L = idx / (512 * 128); int rr = idx - L * 512 * 128;
        int r = rr >> 7, k = rr & 127;
        int srow = (r < 256) ? k : 128 + k;
        int scol = (r < 256) ? r : r - 256;
        pW[(size_t)L * 512 * WK + r * WK + k] = f2bf(ew1[(size_t)L * 257 * 256 + srow * 256 + scol]);
        return;
    }
    idx -= SZ1;
    if (idx < SZ2) {
        int L = idx >> 16, r = idx & 65535, n = r >> 8, k = r & 255;
        nW1T[(size_t)L * 256 * WLD + n * WLD + k] = f2bf(nw1[(size_t)L * 256 * 256 + k * 256 + n]);
        return;
    }
    idx -= SZ2;
    if (idx < SZ3) {
        int L = idx >> 15, r = idx & 32767, n = r >> 8, k = r & 255;
        nW2T[(size_t)L * 128 * WLD + n * WLD + k] = f2bf(nw2[(size_t)L * 256 * 128 + k * 128 + n]);
        return;
    }
    idx -= SZ3;
    if (idx < SZ4) {
        int L = idx >> 8, c = idx & 255;
        int cs = (c & ~63) | ((c & 3) * 16 + ((c >> 2) & 15));
        w1a_p[idx] = ew1[(size_t)L * 257 * 256 + 256 * 256 + cs];
        b1_p[idx]  = eb1[(size_t)L * 256 + cs];
        w2_p[idx]  = ew2[(size_t)L * 256 + cs];
        return;
    }
    idx -= SZ4;
    if (idx < SZH) {
        const float4* p = (const float4*)(h0 + (size_t)idx * 8);
        float4 a = p[0], b = p[1];
        bf16x8 t;
        t[0] = f2bf(a.x); t[1] = f2bf(a.y); t[2] = f2bf(a.z); t[3] = f2bf(a.w);
        t[4] = f2bf(b.x); t[5] = f2bf(b.y); t[6] = f2bf(b.z); t[7] = f2bf(b.w);
        *(bf16x8*)(hb + (size_t)idx * 8) = t;
        int wa = __builtin_amdgcn_cvt_pk_fp8_f32(a.x, a.y, 0, false);
        wa = __builtin_amdgcn_cvt_pk_fp8_f32(a.z, a.w, wa, true);
        int wb = __builtin_amdgcn_cvt_pk_fp8_f32(b.x, b.y, 0, false);
        wb = __builtin_amdgcn_cvt_pk_fp8_f32(b.z, b.w, wb, true);
        *(unsigned*)(h8 + (size_t)idx * 8) = (unsigned)wa;
        *(unsigned*)(h8 + (size_t)idx * 8 + 4) = (unsigned)wb;
        return;
    }
    idx -= SZH;
    if (idx < 2 * LUTN) {
        int i = idx & (LUTN - 1);
        float x = (float)(i - 1024) * (1.0f / 128.0f);
        float v;
        if (idx < LUTN) {
            v = 0.5f * x * (1.0f + erff(x * 0.70710678118654752f));  // exact gelu
        } else {
            v = 1.0f / (1.0f + expf(-x));                            // exact sigmoid
        }
        luts[idx] = v;
        return;
    }
    idx -= 2 * LUTN;
    if (idx < NEDGE) {
        atomicAdd(&deg[ei[2 * idx + 1]], 1);
    }
}

__global__ void csr_scatter(const int* __restrict__ ei, const float* __restrict__ attr,
                            int* __restrict__ cursor, int2* __restrict__ epk) {
    int e = blockIdx.x * 256 + threadIdx.x;
    if (e >= NEDGE) return;
    int s = ei[2 * e], d = ei[2 * e + 1];
    int pos = atomicAdd(&cursor[d], 1);
    int2 pk; pk.x = s; pk.y = __float_as_int(attr[e]);
    epk[pos] = pk;
    if (e == 0) { int2 z; z.x = 0; z.y = 0; epk[NEDGE] = z; }
}

// ---------------- scan as a device function (runs in one 512-thread block of proj L0) ----------------
__device__ void scan_block512(const int* __restrict__ deg, int* __restrict__ rowptr,
                              int* __restrict__ cursor) {
    __shared__ int wsum[8];
    __shared__ int carry_s;
    const int tid = threadIdx.x, lane = tid & 63, wv = tid >> 6;
    if (tid == 0) carry_s = 0;
    __syncthreads();
    for (int base = 0; base < NNODE; base += 2048) {
        int i0 = base + tid * 4;
        int v0 = 0, v1 = 0, v2 = 0, v3 = 0;
        if (i0 + 3 < NNODE) {
            int4 q = *(const int4*)(deg + i0);
            v0 = q.x; v1 = q.y; v2 = q.z; v3 = q.w;
        } else if (i0 < NNODE) {
            v0 = deg[i0];
            if (i0 + 1 < NNODE) v1 = deg[i0 + 1];
            if (i0 + 2 < NNODE) v2 = deg[i0 + 2];
        }
        int tsum = v0 + v1 + v2 + v3;
        int x = tsum;
#pragma unroll
        for (int off = 1; off < 64; off <<= 1) {
            int y = __shfl_up(x, off);
            if (lane >= off) x += y;
        }
        if (lane == 63) wsum[wv] = x;
        __syncthreads();
        if (wv == 0) {
            int s = (lane < 8) ? wsum[lane] : 0;
#pragma unroll
            for (int off = 1; off < 8; off <<= 1) {
                int y = __shfl_up(s, off);
                if (lane >= off) s += y;
            }
            if (lane < 8) wsum[lane] = s;
        }
        __syncthreads();
        int carry = carry_s;
        int woff = wv ? wsum[wv - 1] : 0;
        int e0 = carry + woff + (x - tsum);
        if (i0 < NNODE)     { rowptr[i0] = e0;                cursor[i0] = e0; }
        if (i0 + 1 < NNODE) { int v = e0 + v0;                rowptr[i0+1] = v; cursor[i0+1] = v; }
        if (i0 + 2 < NNODE) { int v = e0 + v0 + v1;           rowptr[i0+2] = v; cursor[i0+2] = v; }
        if (i0 + 3 < NNODE) { int v = e0 + v0 + v1 + v2;      rowptr[i0+3] = v; cursor[i0+3] = v; }
        int total = wsum[7];
        __syncthreads();
        if (tid == 0) carry_s = carry + total;
        __syncthreads();
    }
    if (tid == 0) rowptr[NNODE] = carry_s;
}

// ---------------- proj: Ps(fp8) = h@W1s, Pd(bf16) = h@W1d; extra block runs the CSR scan ----------------
__global__ __launch_bounds__(512, 2)
void proj_kernel(const short* __restrict__ hb,    // [N][128] bf16
                 const short* __restrict__ pW,    // [512][WK]
                 unsigned char* __restrict__ Ps8, // [N][256] fp8 e4m3 (permuted cols)
                 short* __restrict__ Pd,          // [N][256] bf16 (permuted cols)
                 const int* __restrict__ deg, int* __restrict__ rowptr,
                 int* __restrict__ cursor)
{
    if (blockIdx.x >= PROJ_BLOCKS) {            // scan block (present only in the L0 launch)
        scan_block512(deg, rowptr, cursor);
        return;
    }

    __shared__ short A[64][WK];
    const int tid = threadIdx.x;
    const int n0 = blockIdx.x * 64;

    for (int idx = tid; idx < 64 * 16; idx += 512) {
        int nl = idx >> 4, q = idx & 15;
        int gn = min(n0 + nl, NNODE - 1);
        *(bf16x8*)&A[nl][q * 8] = *(const bf16x8*)(hb + (size_t)gn * DIM + q * 8);
    }
    __syncthreads();

    const int lane = tid & 63;
    const int wv = tid >> 6;     // 0..7; wv<4 -> Ps cols, wv>=4 -> Pd cols
    const int lrow = lane & 15;
    const int lkg = lane >> 4;

    f32x4 acc[4][4];
#pragma unroll
    for (int mi = 0; mi < 4; ++mi)
#pragma unroll
        for (int ni = 0; ni < 4; ++ni) acc[mi][ni] = (f32x4){0.f, 0.f, 0.f, 0.f};

    const short* xbase = &A[lrow][lkg * 8];
    const short* wbase = pW + (size_t)(wv * 64 + lrow) * WK + lkg * 8;

#pragma unroll
    for (int kt = 0; kt < 4; ++kt) {
        bf16x8 a[4], b[4];
#pragma unroll
        for (int mi = 0; mi < 4; ++mi)
            a[mi] = *(const bf16x8*)(xbase + mi * 16 * WK + kt * 32);
#pragma unroll
        for (int ni = 0; ni < 4; ++ni)
            b[ni] = *(const bf16x8*)(wbase + ni * 16 * WK + kt * 32);
#pragma unroll
        for (int mi = 0; mi < 4; ++mi)
#pragma unroll
            for (int ni = 0; ni < 4; ++ni)
                acc[mi][ni] = __builtin_amdgcn_mfma_f32_16x16x32_bf16(a[mi], b[ni], acc[mi][ni], 0, 0, 0);
    }

    const int cb = (wv & 3) * 64;
    if (wv < 4) {
#pragma unroll
        for (int mi = 0; mi < 4; ++mi)
#pragma unroll
            for (int reg = 0; reg < 4; ++reg) {
                int node = n0 + mi * 16 + lkg * 4 + reg;
                int w = __builtin_amdgcn_cvt_pk_fp8_f32(acc[mi][0][reg], acc[mi][1][reg], 0, false);
                w = __builtin_amdgcn_cvt_pk_fp8_f32(acc[mi][2][reg], acc[mi][3][reg], w, true);
                if (node < NNODE)
                    *(unsigned*)(Ps8 + (size_t)node * 256 + cb + lrow * 4) = (unsigned)w;
            }
    } else {
#pragma unroll
        for (int mi = 0; mi < 4; ++mi)
#pragma unroll
            for (int reg = 0; reg < 4; ++reg) {
                int node = n0 + mi * 16 + lkg * 4 + reg;
                bf16x4 t;
                t[0] = f2bf(acc[mi][0][reg]);
                t[1] = f2bf(acc[mi][1][reg]);
                t[2] = f2bf(acc[mi][2][reg]);
                t[3] = f2bf(acc[mi][3][reg]);
                if (node < NNODE)
                    *(bf16x4*)(Pd + (size_t)node * 256 + cb + lrow * 4) = t;
            }
    }
}

// ---------------- fused edge-gate + aggregate: one wave per dst node, 4 edges/iteration ----------------
// 16-lane groups: group g handles edge 4t+g; lane covers 16 hidden cols (one
// dwordx4 fp8 load) and 8 h-dims (one dwordx2 fp8 load). Gate reduce = 4
// shfl_xor within the group; cross-group combine of agg/den once at the end.
__global__ __launch_bounds__(256)
void edge_agg(const unsigned char* __restrict__ Ps8, const short* __restrict__ Pd,
              const unsigned char* __restrict__ h8,
              const int2* __restrict__ epk, const int* __restrict__ rowptr,
              const float* __restrict__ w1a_p, const float* __restrict__ b1_p,
              const float* __restrict__ w2_p, const float* __restrict__ b2,
              const float* __restrict__ luts,
              short* __restrict__ u2)          // aliases Pd: row stride 256, first 128 cols
{
    __shared__ float sg[LUTN];   // gelu table
    __shared__ float ss[LUTN];   // sigmoid table

    const int tid = threadIdx.x;
#pragma unroll
    for (int i = 0; i < LUTN / 256; ++i) {
        sg[tid + i * 256] = luts[tid + i * 256];
        ss[tid + i * 256] = luts[LUTN + tid + i * 256];
    }
    __syncthreads();

    const int node = (blockIdx.x * 256 + tid) >> 6;
    const int lane = tid & 63;
    const int ll  = lane & 15;   // lane within 16-lane group
    const int grp = lane >> 4;   // group 0..3

    const int beg = __builtin_amdgcn_readfirstlane(rowptr[node]);
    const int end = __builtin_amdgcn_readfirstlane(rowptr[node + 1]);
    const int d = end - beg;

    const float b2s = b2[0];

    // per-lane constants for its 16 storage cols [ll*16, ll*16+16)
    float w1a[16], w2c[16], pdb[16];
#pragma unroll
    for (int k = 0; k < 4; ++k) {
        float4 ta = ((const float4*)w1a_p)[ll * 4 + k];
        float4 tb = ((const float4*)b1_p)[ll * 4 + k];
        float4 tc = ((const float4*)w2_p)[ll * 4 + k];
        w1a[4 * k + 0] = ta.x; w1a[4 * k + 1] = ta.y; w1a[4 * k + 2] = ta.z; w1a[4 * k + 3] = ta.w;
        pdb[4 * k + 0] = tb.x; pdb[4 * k + 1] = tb.y; pdb[4 * k + 2] = tb.z; pdb[4 * k + 3] = tb.w;
        w2c[4 * k + 0] = tc.x; w2c[4 * k + 1] = tc.y; w2c[4 * k + 2] = tc.z; w2c[4 * k + 3] = tc.w;
    }
    {
        bf16x8 pd0 = *(const bf16x8*)(Pd + (size_t)node * 256 + ll * 16);
        bf16x8 pd1 = *(const bf16x8*)(Pd + (size_t)node * 256 + ll * 16 + 8);
#pragma unroll
        for (int j = 0; j < 8; ++j) pdb[j] += bf2f(pd0[j]);
#pragma unroll
        for (int j = 0; j < 8; ++j) pdb[8 + j] += bf2f(pd1[j]);
    }

    float ax[8];
#pragma unroll
    for (int j = 0; j < 8; ++j) ax[j] = 0.f;
    float den = 0.f;

    const unsigned pso = (unsigned)(ll * 16);   // bytes within Ps8 row
    const unsigned hvo = (unsigned)(ll * 8);    // bytes within h8 row

    for (int base = 0; base < d; base += 64) {
        const int cn = min(64, d - base);
        const int cl = cn - 1;
        int2 sa0 = epk[beg + base + min(lane, cl)];
        int sl = sa0.x;
        float al = __int_as_float(sa0.y);
        const int iters = (cn + 3) >> 2;

        // prefetch iteration 0
        int eA = grp;
        int srcA = __shfl(sl, min(eA, cl));
        float aA = __shfl(al, min(eA, cl));
        uint4 psA = *(const uint4*)(Ps8 + (((size_t)(unsigned)srcA) << 8) + pso);
        uint2 hA  = *(const uint2*)(h8 + (((size_t)(unsigned)srcA) << 7) + hvo);

        for (int t = 0; t < iters; ++t) {
            // prefetch next iteration (clamped; harmless duplicate on last)
            int eB = ((t + 1) << 2) + grp;
            int srcB = __shfl(sl, min(eB, cl));
            float aB = __shfl(al, min(eB, cl));
            uint4 psB = *(const uint4*)(Ps8 + (((size_t)(unsigned)srcB) << 8) + pso);
            uint2 hB  = *(const uint2*)(h8 + (((size_t)(unsigned)srcB) << 7) + hvo);

            // gate: x = ps + pdb + a*w1a over this lane's 16 cols
            float p = 0.f;
            {
                unsigned dw[4] = {psA.x, psA.y, psA.z, psA.w};
#pragma unroll
                for (int k = 0; k < 4; ++k) {
                    f32x2 lo = __builtin_amdgcn_cvt_pk_f32_fp8((int)dw[k], false);
                    f32x2 hi = __builtin_amdgcn_cvt_pk_f32_fp8((int)dw[k], true);
                    float x0 = lo[0] + pdb[4 * k + 0] + aA * w1a[4 * k + 0];
                    float x1 = lo[1] + pdb[4 * k + 1] + aA * w1a[4 * k + 1];
                    float x2 = hi[0] + pdb[4 * k + 2] + aA * w1a[4 * k + 2];
                    float x3 = hi[1] + pdb[4 * k + 3] + aA * w1a[4 * k + 3];
                    p += lut_look(sg, x0) * w2c[4 * k + 0];
                    p += lut_look(sg, x1) * w2c[4 * k + 1];
                    p += lut_look(sg, x2) * w2c[4 * k + 2];
                    p += lut_look(sg, x3) * w2c[4 * k + 3];
                }
            }
            // reduce within the 16-lane group
            p += __shfl_xor(p, 1);
            p += __shfl_xor(p, 2);
            p += __shfl_xor(p, 4);
            p += __shfl_xor(p, 8);
            float g = lut_look(ss, p + b2s);
            if (((t << 2) + grp) >= cn) g = 0.f;   // mask padded edges

            // aggregate this group's edge: 8 h-dims per lane
            {
                f32x2 h01 = __builtin_amdgcn_cvt_pk_f32_fp8((int)hA.x, false);
                f32x2 h23 = __builtin_amdgcn_cvt_pk_f32_fp8((int)hA.x, true);
                f32x2 h45 = __builtin_amdgcn_cvt_pk_f32_fp8((int)hA.y, false);
                f32x2 h67 = __builtin_amdgcn_cvt_pk_f32_fp8((int)hA.y, true);
                ax[0] = fmaf(g, h01[0], ax[0]);
                ax[1] = fmaf(g, h01[1], ax[1]);
                ax[2] = fmaf(g, h23[0], ax[2]);
                ax[3] = fmaf(g, h23[1], ax[3]);
                ax[4] = fmaf(g, h45[0], ax[4]);
                ax[5] = fmaf(g, h45[1], ax[5]);
                ax[6] = fmaf(g, h67[0], ax[6]);
                ax[7] = fmaf(g, h67[1], ax[7]);
                den += g;
            }

            psA = psB; hA = hB; aA = aB;
        }
    }

    // cross-group combine (groups hold disjoint edges, same dims)
#pragma unroll
    for (int j = 0; j < 8; ++j) {
        ax[j] += __shfl_xor(ax[j], 16);
        ax[j] += __shfl_xor(ax[j], 32);
    }
    den += __shfl_xor(den, 16);
    den += __shfl_xor(den, 32);

    float dd = fmaxf(den, 1e-6f);
    float dinv = __builtin_amdgcn_rcpf(dd);
    dinv = dinv * (2.0f - dd * dinv);

    if (grp == 0) {
        uint4 o;
        o.x = (((unsigned)(unsigned short)f2bf(ax[1] * dinv)) << 16) | (unsigned)(unsigned short)f2bf(ax[0] * dinv);
        o.y = (((unsigned)(unsigned short)f2bf(ax[3] * dinv)) << 16) | (unsigned)(unsigned short)f2bf(ax[2] * dinv);
        o.z = (((unsigned)(unsigned short)f2bf(ax[5] * dinv)) << 16) | (unsigned)(unsigned short)f2bf(ax[4] * dinv);
        o.w = (((unsigned)(unsigned short)f2bf(ax[7] * dinv)) << 16) | (unsigned)(unsigned short)f2bf(ax[6] * dinv);
        *(uint4*)(u2 + (size_t)node * 256 + ll * 8) = o;
    }
}

// ---------------- node MLP: 64 nodes/block, SINGLE LDS buffer (U -> G -> R) ----------------
__global__ __launch_bounds__(256, 4)
void node_mlp(const float* __restrict__ hin,   // f32 residual
              const short* __restrict__ hb,    // bf16
              const short* __restrict__ u2,    // bf16 agg, row stride 256
              const short* __restrict__ W1T,   // [256][WLD]
              const float* __restrict__ b1,
              const short* __restrict__ W2T,   // [128][WLD]
              const float* __restrict__ b2,
              const float* __restrict__ lng, const float* __restrict__ lnb,
              float* __restrict__ hout, short* __restrict__ hb_out,
              unsigned char* __restrict__ h8_out)
{
    __shared__ short U[64][WLD];   // 33792 B: staged U, then G (gelu), then R (f32 overlay)

    const int tid = threadIdx.x;
    const int n0 = blockIdx.x * 64;
    const int lane = tid & 63;
    const int wv = tid >> 6;

    for (int idx = tid; idx < 64 * 32; idx += 256) {
        int nl = idx >> 5, q = idx & 31;
        int gn = min(n0 + nl, NNODE - 1);
        const short* src = (q < 16) ? (hb + (size_t)gn * DIM + q * 8)
                                    : (u2 + (size_t)gn * 256 + (q - 16) * 8);
        *(bf16x8*)&U[nl][q * 8] = *(const bf16x8*)src;
    }
    __syncthreads();

    const int lrow = lane & 15;
    const int lkg = lane >> 4;
    const int n0w = wv * 64;

    // GEMM1: [64][256] x [256][256], acc in regs
    f32x4 acc1[4][4];
#pragma unroll
    for (int mi = 0; mi < 4; ++mi)
#pragma unroll
        for (int ni = 0; ni < 4; ++ni) acc1[mi][ni] = (f32x4){0.f, 0.f, 0.f, 0.f};
    {
        const short* xbase = &U[lrow][lkg * 8];
        const short* wbase = W1T + (size_t)(n0w + lrow) * WLD + lkg * 8;
#pragma unroll
        for (int kt = 0; kt < 8; ++kt) {
            bf16x8 a[4], b[4];
#pragma unroll
            for (int mi = 0; mi < 4; ++mi)
                a[mi] = *(const bf16x8*)(xbase + mi * 16 * WLD + kt * 32);
#pragma unroll
            for (int ni = 0; ni < 4; ++ni)
                b[ni] = *(const bf16x8*)(wbase + ni * 16 * WLD + kt * 32);
#pragma unroll
            for (int mi = 0; mi < 4; ++mi)
#pragma unroll
                for (int ni = 0; ni < 4; ++ni)
                    acc1[mi][ni] = __builtin_amdgcn_mfma_f32_16x16x32_bf16(a[mi], b[ni], acc1[mi][ni], 0, 0, 0);
        }
    }
    __syncthreads();   // all U reads complete before overwrite

    // write G = gelu(acc1 + b1) over the same buffer (fast sigmoid-approx gelu)
    {
        float b1v[4];
#pragma unroll
        for (int ni = 0; ni < 4; ++ni) b1v[ni] = b1[n0w + ni * 16 + lrow];
#pragma unroll
        for (int mi = 0; mi < 4; ++mi)
#pragma unroll
            for (int ni = 0; ni < 4; ++ni)
#pragma unroll
                for (int reg = 0; reg < 4; ++reg) {
                    int row = mi * 16 + lkg * 4 + reg;
                    int col = n0w + ni * 16 + lrow;
                    U[row][col] = f2bf(gelu_fast(acc1[mi][ni][reg] + b1v[ni]));
                }
    }
    __syncthreads();

    // GEMM2: [64][256] x [256][128], acc in regs (buffer still holds G)
    f32x4 acc2[4][2];
#pragma unroll
    for (int mi = 0; mi < 4; ++mi)
#pragma unroll
        for (int ni = 0; ni < 2; ++ni) acc2[mi][ni] = (f32x4){0.f, 0.f, 0.f, 0.f};
    {
        const short* xbase = &U[lrow][lkg * 8];
        const short* wbase = W2T + (size_t)(wv * 32 + lrow) * WLD + lkg * 8;
#pragma unroll
        for (int kt = 0; kt < 8; ++kt) {
            bf16x8 a[4], b[2];
#pragma unroll
            for (int mi = 0; mi < 4; ++mi)
                a[mi] = *(const bf16x8*)(xbase + mi * 16 * WLD + kt * 32);
#pragma unroll
            for (int ni = 0; ni < 2; ++ni)
                b[ni] = *(const bf16x8*)(wbase + ni * 16 * WLD + kt * 32);
#pragma unroll
            for (int mi = 0; mi < 4; ++mi)
#pragma unroll
                for (int ni = 0; ni < 2; ++ni)
                    acc2[mi][ni] = __builtin_amdgcn_mfma_f32_16x16x32_bf16(a[mi], b[ni], acc2[mi][ni], 0, 0, 0);
        }
    }
    __syncthreads();   // all G reads complete before R overlay

    // R f32 overlay [64][132] over the same buffer
    float* R = (float*)&U[0][0];
    {
        float b2v[2];
#pragma unroll
        for (int ni = 0; ni < 2; ++ni) b2v[ni] = b2[wv * 32 + ni * 16 + lrow];
#pragma unroll
        for (int mi = 0; mi < 4; ++mi)
#pragma unroll
            for (int ni = 0; ni < 2; ++ni)
#pragma unroll
                for (int reg = 0; reg < 4; ++reg) {
                    int row = mi * 16 + lkg * 4 + reg;
                    int col = wv * 32 + ni * 16 + lrow;
                    R[row * 132 + col] = acc2[mi][ni][reg] + b2v[ni];
                }
    }
    __syncthreads();

    // residual + LayerNorm; write hout f32 + hb bf16 + h8 fp8
#pragma unroll
    for (int ii = 0; ii < 16; ++ii) {
        int nl = wv * 16 + ii;
        int gn = n0 + nl;
        int gnc = min(gn, NNODE - 1);
        float rx = R[nl * 132 + lane * 2 + 0];
        float ry = R[nl * 132 + lane * 2 + 1];
        const float2 hh = *(const float2*)(hin + (size_t)gnc * DIM + lane * 2);
        float vx = rx + hh.x, vy = ry + hh.y;
        float s = vx + vy;
#pragma unroll
        for (int off = 32; off > 0; off >>= 1) s += __shfl_xor(s, off);
        float mu = s * (1.0f / 128.0f);
        float dx = vx - mu, dy = vy - mu;
        float q = dx * dx + dy * dy;
#pragma unroll
        for (int off = 32; off > 0; off >>= 1) q += __shfl_xor(q, off);
        float inv = rsqrtf(q * (1.0f / 128.0f) + 1e-5f);
        if (gn < NNODE) {
            const float2 gg = *(const float2*)(lng + lane * 2);
            const float2 bb = *(const float2*)(lnb + lane * 2);
            float ox = dx * inv * gg.x + bb.x;
            float oy = dy * inv * gg.y + bb.y;
            *(float2*)(hout + (size_t)gn * DIM + lane * 2) = make_float2(ox, oy);
            unsigned pk = ((unsigned)(unsigned short)f2bf(oy) << 16) |
                          (unsigned)(unsigned short)f2bf(ox);
            *(unsigned*)(hb_out + (size_t)gn * DIM + lane * 2) = pk;
            int w8 = __builtin_amdgcn_cvt_pk_fp8_f32(ox, oy, 0, false);
            *(unsigned short*)(h8_out + (size_t)gn * DIM + lane * 2) = (unsigned short)(w8 & 0xFFFF);
        }
    }
}

extern "C" void kernel_launch(void* const* d_in, const int* in_sizes, int n_in,
                              void* d_out, int out_size, void* d_ws, size_t ws_size,
                              hipStream_t stream) {
    const float* h0   = (const float*)d_in[0];
    const int*   ei   = (const int*)d_in[1];
    const float* attr = (const float*)d_in[2];
    const float* ew1  = (const float*)d_in[3];
    const float* eb1  = (const float*)d_in[4];
    const float* ew2  = (const float*)d_in[5];
    const float* eb2  = (const float*)d_in[6];
    const float* nw1  = (const float*)d_in[7];
    const float* nb1  = (const float*)d_in[8];
    const float* nw2  = (const float*)d_in[9];
    const float* nb2  = (const float*)d_in[10];
    const float* lng  = (const float*)d_in[11];
    const float* lnb  = (const float*)d_in[12];

    float* hout = (float*)d_out;

    char* p = (char*)d_ws;
    int*   rowptr = (int*)p;               p += sizeof(int) * (NNODE + 4);
    int*   cursor = (int*)p;               p += sizeof(int) * (NNODE + 4);
    int*   deg    = (int*)p;               p += sizeof(int) * (NNODE + 4);
    int2*  epk    = (int2*)p;              p += sizeof(int2) * (NEDGE + 1);
    short* hb     = (short*)p;             p += sizeof(short) * (size_t)NNODE * DIM;
    unsigned char* h8 = (unsigned char*)p; p += (size_t)NNODE * DIM;
    unsigned char* Ps8 = (unsigned char*)p; p += (size_t)NNODE * 256;
    short* Pd     = (short*)p;             p += sizeof(short) * (size_t)NNODE * 256;
    short* u2     = Pd;                    // alias: each wave reads only its own Pd row, then writes u2 there
    short* pW     = (short*)p;             p += sizeof(short) * (size_t)NLAYERS * 512 * WK;
    short* nW1T   = (short*)p;             p += sizeof(short) * (size_t)NLAYERS * 256 * WLD;
    short* nW2T   = (short*)p;             p += sizeof(short) * (size_t)NLAYERS * 128 * WLD;
    float* w1a_p  = (float*)p;             p += sizeof(float) * NLAYERS * 256;
    float* b1_p   = (float*)p;             p += sizeof(float) * NLAYERS * 256;
    float* w2_p   = (float*)p;             p += sizeof(float) * NLAYERS * 256;
    float* luts   = (float*)p;             p += sizeof(float) * 2 * LUTN;

    const int PREP_TOTAL = NLAYERS * 512 * 128 + NLAYERS * 256 * 256 +
                           NLAYERS * 128 * 256 + NLAYERS * 256 + NNODE * DIM / 8 +
                           2 * LUTN + NEDGE;

    hipMemsetAsync(deg, 0, (NNODE + 1) * sizeof(int), stream);
    prep_weights<<<(PREP_TOTAL + 255) / 256, 256, 0, stream>>>(
        ew1, eb1, ew2, nw1, nw2, h0, ei, pW, nW1T, nW2T, w1a_p, b1_p, w2_p, hb, h8, luts, deg);

    for (int L = 0; L < NLAYERS; ++L) {
        const float* hin = (L == 0) ? h0 : hout;
        proj_kernel<<<PROJ_BLOCKS + (L == 0 ? 1 : 0), 512, 0, stream>>>(
            hb, pW + (size_t)L * 512 * WK, Ps8, Pd, deg, rowptr, cursor);
        if (L == 0)
            csr_scatter<<<(NEDGE + 255) / 256, 256, 0, stream>>>(ei, attr, cursor, epk);
        edge_agg<<<NNODE / 4, 256, 0, stream>>>(
            Ps8, Pd, h8, epk, rowptr,
            w1a_p + (size_t)L * 256, b1_p + (size_t)L * 256,
            w2_p + (size_t)L * 256, eb2 + L, luts, u2);
        node_mlp<<<(NNODE + 63) / 64, 256, 0, stream>>>(
            hin, hb, u2,
            nW1T + (size_t)L * 256 * WLD, nb1 + (size_t)L * 256,
            nW2T + (size_t)L * 128 * WLD, nb2 + (size_t)L * 128,
            lng + (size_t)L * DIM, lnb + (size_t)L * DIM,
            hout, hb, h8);
    }
}

// Round 15
// 511.504 us; speedup vs baseline: 1.2431x; 1.2431x over previous
//
#include <hip/hip_runtime.h>
#include <math.h>

#define NNODE 100000
#define NEDGE 600000
#define DIM 128
#define HID 256
#define NLAYERS 2

typedef short bf16x8 __attribute__((ext_vector_type(8)));
typedef short bf16x4 __attribute__((ext_vector_type(4)));
typedef float f32x4 __attribute__((ext_vector_type(4)));
typedef float f32x2 __attribute__((ext_vector_type(2)));

#define WK 136    // proj weight LD (k=128 + pad)
#define WLD 264   // node weight / LDS tile LD (k=256 + pad)
#define LUTN 2048 // entries per table, domain [-8,8), step 1/128
#define SCAN_CHUNK 4096
#define SCAN_BLOCKS ((NNODE + SCAN_CHUNK - 1) / SCAN_CHUNK)   // 25

__device__ __forceinline__ short f2bf(float x) {
    union { float f; unsigned u; } v; v.f = x;
    unsigned r = v.u + 0x7FFFu + ((v.u >> 16) & 1u);
    return (short)(r >> 16);
}
__device__ __forceinline__ float bf2f(short s) {
    union { unsigned u; float f; } v; v.u = ((unsigned)(unsigned short)s) << 16;
    return v.f;
}
// accurate gelu (A&S erf) for node MLP
__device__ __forceinline__ float gelu_erf(float x) {
    float z = x * 0.70710678118654752f;
    float az = fabsf(z);
    float t = __builtin_amdgcn_rcpf(1.0f + 0.3275911f * az);
    float y = t * (0.254829592f + t * (-0.284496736f + t * (1.421413741f +
              t * (-1.453152027f + t * 1.061405429f))));
    float e = __expf(-az * az);
    float er = 1.0f - y * e;
    er = copysignf(er, z);
    return 0.5f * x * (1.0f + er);
}
// LDS LUT lookup: value at nearest grid point of [-8,8) step 1/128
__device__ __forceinline__ float lut_look(const float* __restrict__ lut, float x) {
    float t = fmaf(x, 128.f, 1024.5f);
    t = fminf(fmaxf(t, 0.f), 2047.f);
    return lut[(int)t];
}

// ---------------- prep: weights -> bf16 transposed + permuted edge vectors + h0->bf16/fp8 + LUTs + deg hist ----------------
__global__ void prep_weights(const float* __restrict__ ew1,   // [L][257][256]
                             const float* __restrict__ eb1,   // [L][256]
                             const float* __restrict__ ew2,   // [L][256][1]
                             const float* __restrict__ nw1,   // [L][256][256]
                             const float* __restrict__ nw2,   // [L][256][128]
                             const float* __restrict__ h0,    // [N][128] f32
                             const int* __restrict__ ei,      // [E][2]
                             short* __restrict__ pW,          // [L][512][WK]
                             short* __restrict__ nW1T,        // [L][256][WLD]
                             short* __restrict__ nW2T,        // [L][128][WLD]
                             float* __restrict__ w1a_p,       // [L][256] permuted
                             float* __restrict__ b1_p,        // [L][256] permuted
                             float* __restrict__ w2_p,        // [L][256] permuted
                             short* __restrict__ hb,          // [N][128] bf16
                             unsigned char* __restrict__ h8,  // [N][128] fp8 e4m3
                             float* __restrict__ luts,        // [2*LUTN]: gelu | sigmoid
                             int* __restrict__ deg)
{
    int idx = blockIdx.x * 256 + threadIdx.x;
    const int SZ1 = NLAYERS * 512 * 128;
    const int SZ2 = NLAYERS * 256 * 256;
    const int SZ3 = NLAYERS * 128 * 256;
    const int SZ4 = NLAYERS * 256;
    const int SZH = NNODE * DIM / 8;
    if (idx < SZ1) {
        int L = idx / (512 * 128); int rr = idx - L * 512 * 128;
        int r = rr >> 7, k = rr & 127;
        int srow = (r < 256) ? k : 128 + k;
        int scol = (r < 256) ? r : r - 256;
        pW[(size_t)L * 512 * WK + r * WK + k] = f2bf(ew1[(size_t)L * 257 * 256 + srow * 256 + scol]);
        return;
    }
    idx -= SZ1;
    if (idx < SZ2) {
        int L = idx >> 16, r = idx & 65535, n = r >> 8, k = r & 255;
        nW1T[(size_t)L * 256 * WLD + n * WLD + k] = f2bf(nw1[(size_t)L * 256 * 256 + k * 256 + n]);
        return;
    }
    idx -= SZ2;
    if (idx < SZ3) {
        int L = idx >> 15, r = idx & 32767, n = r >> 8, k = r & 255;
        nW2T[(size_t)L * 128 * WLD + n * WLD + k] = f2bf(nw2[(size_t)L * 256 * 128 + k * 128 + n]);
        return;
    }
    idx -= SZ3;
    if (idx < SZ4) {
        int L = idx >> 8, c = idx & 255;
        int cs = (c & ~63) | ((c & 3) * 16 + ((c >> 2) & 15));
        w1a_p[idx] = ew1[(size_t)L * 257 * 256 + 256 * 256 + cs];
        b1_p[idx]  = eb1[(size_t)L * 256 + cs];
        w2_p[idx]  = ew2[(size_t)L * 256 + cs];
        return;
    }
    idx -= SZ4;
    if (idx < SZH) {
        const float4* p = (const float4*)(h0 + (size_t)idx * 8);
        float4 a = p[0], b = p[1];
        bf16x8 t;
        t[0] = f2bf(a.x); t[1] = f2bf(a.y); t[2] = f2bf(a.z); t[3] = f2bf(a.w);
        t[4] = f2bf(b.x); t[5] = f2bf(b.y); t[6] = f2bf(b.z); t[7] = f2bf(b.w);
        *(bf16x8*)(hb + (size_t)idx * 8) = t;
        int wa = __builtin_amdgcn_cvt_pk_fp8_f32(a.x, a.y, 0, false);
        wa = __builtin_amdgcn_cvt_pk_fp8_f32(a.z, a.w, wa, true);
        int wb = __builtin_amdgcn_cvt_pk_fp8_f32(b.x, b.y, 0, false);
        wb = __builtin_amdgcn_cvt_pk_fp8_f32(b.z, b.w, wb, true);
        *(unsigned*)(h8 + (size_t)idx * 8) = (unsigned)wa;
        *(unsigned*)(h8 + (size_t)idx * 8 + 4) = (unsigned)wb;
        return;
    }
    idx -= SZH;
    if (idx < 2 * LUTN) {
        int i = idx & (LUTN - 1);
        float x = (float)(i - 1024) * (1.0f / 128.0f);
        float v;
        if (idx < LUTN) {
            v = 0.5f * x * (1.0f + erff(x * 0.70710678118654752f));  // exact gelu
        } else {
            v = 1.0f / (1.0f + expf(-x));                            // exact sigmoid
        }
        luts[idx] = v;
        return;
    }
    idx -= 2 * LUTN;
    if (idx < NEDGE) {
        atomicAdd(&deg[ei[2 * idx + 1]], 1);
    }
}

// ---------------- CSR build: 3-phase parallel scan ----------------
__global__ __launch_bounds__(1024)
void scan_part1(const int* __restrict__ deg, int* __restrict__ bsum) {
    __shared__ int wsum[16];
    const int tid = threadIdx.x, lane = tid & 63, wv = tid >> 6;
    int i0 = blockIdx.x * SCAN_CHUNK + tid * 4;
    int v = 0;
    if (i0 + 3 < NNODE) {
        int4 q = *(const int4*)(deg + i0);
        v = q.x + q.y + q.z + q.w;
    } else if (i0 < NNODE) {
        v = deg[i0];
        if (i0 + 1 < NNODE) v += deg[i0 + 1];
        if (i0 + 2 < NNODE) v += deg[i0 + 2];
    }
#pragma unroll
    for (int off = 32; off > 0; off >>= 1) v += __shfl_xor(v, off);
    if (lane == 0) wsum[wv] = v;
    __syncthreads();
    if (tid == 0) {
        int s = 0;
#pragma unroll
        for (int w = 0; w < 16; ++w) s += wsum[w];
        bsum[blockIdx.x] = s;
    }
}

__global__ void scan_part2(int* __restrict__ bsum, int* __restrict__ rowptr) {
    const int lane = threadIdx.x;
    int v = (lane < SCAN_BLOCKS) ? bsum[lane] : 0;
    int x = v;
#pragma unroll
    for (int off = 1; off < 64; off <<= 1) {
        int y = __shfl_up(x, off);
        if (lane >= off) x += y;
    }
    if (lane < SCAN_BLOCKS) bsum[lane] = x - v;   // exclusive
    if (lane == 0) rowptr[NNODE] = NEDGE;
}

__global__ __launch_bounds__(1024)
void scan_part3(const int* __restrict__ deg, const int* __restrict__ bsum,
                int* __restrict__ rowptr, int* __restrict__ cursor) {
    __shared__ int wsum[16];
    const int tid = threadIdx.x, lane = tid & 63, wv = tid >> 6;
    int i0 = blockIdx.x * SCAN_CHUNK + tid * 4;
    int v0 = 0, v1 = 0, v2 = 0, v3 = 0;
    if (i0 + 3 < NNODE) {
        int4 q = *(const int4*)(deg + i0);
        v0 = q.x; v1 = q.y; v2 = q.z; v3 = q.w;
    } else if (i0 < NNODE) {
        v0 = deg[i0];
        if (i0 + 1 < NNODE) v1 = deg[i0 + 1];
        if (i0 + 2 < NNODE) v2 = deg[i0 + 2];
    }
    int tsum = v0 + v1 + v2 + v3;
    int x = tsum;
#pragma unroll
    for (int off = 1; off < 64; off <<= 1) {
        int y = __shfl_up(x, off);
        if (lane >= off) x += y;
    }
    if (lane == 63) wsum[wv] = x;
    __syncthreads();
    if (wv == 0) {
        int s = (lane < 16) ? wsum[lane] : 0;
#pragma unroll
        for (int off = 1; off < 16; off <<= 1) {
            int y = __shfl_up(s, off);
            if (lane >= off) s += y;
        }
        if (lane < 16) wsum[lane] = s;
    }
    __syncthreads();
    int carry = bsum[blockIdx.x];
    int woff = wv ? wsum[wv - 1] : 0;
    int e0 = carry + woff + (x - tsum);
    if (i0 < NNODE)     { rowptr[i0] = e0;           cursor[i0] = e0; }
    if (i0 + 1 < NNODE) { int v = e0 + v0;           rowptr[i0+1] = v; cursor[i0+1] = v; }
    if (i0 + 2 < NNODE) { int v = e0 + v0 + v1;      rowptr[i0+2] = v; cursor[i0+2] = v; }
    if (i0 + 3 < NNODE) { int v = e0 + v0 + v1 + v2; rowptr[i0+3] = v; cursor[i0+3] = v; }
}

__global__ void csr_scatter(const int* __restrict__ ei, const float* __restrict__ attr,
                            int* __restrict__ cursor, int2* __restrict__ epk) {
    int e = blockIdx.x * 256 + threadIdx.x;
    if (e >= NEDGE) return;
    int s = ei[2 * e], d = ei[2 * e + 1];
    int pos = atomicAdd(&cursor[d], 1);
    int2 pk; pk.x = s; pk.y = __float_as_int(attr[e]);
    epk[pos] = pk;
    if (e < 4) { int2 z; z.x = 0; z.y = 0; epk[NEDGE + e] = z; }  // sentinels for 2-deep prefetch
}

// ---------------- proj: Ps(fp8) = h@W1s, Pd(bf16) = h@W1d (permuted column layout) ----------------
__global__ __launch_bounds__(512, 2)
void proj_kernel(const short* __restrict__ hb,    // [N][128] bf16
                 const short* __restrict__ pW,    // [512][WK]
                 unsigned char* __restrict__ Ps8, // [N][256] fp8 e4m3 (permuted cols)
                 short* __restrict__ Pd)          // [N][256] bf16 (permuted cols)
{
    __shared__ short A[64][WK];
    const int tid = threadIdx.x;
    const int n0 = blockIdx.x * 64;

    for (int idx = tid; idx < 64 * 16; idx += 512) {
        int nl = idx >> 4, q = idx & 15;
        int gn = min(n0 + nl, NNODE - 1);
        *(bf16x8*)&A[nl][q * 8] = *(const bf16x8*)(hb + (size_t)gn * DIM + q * 8);
    }
    __syncthreads();

    const int lane = tid & 63;
    const int wv = tid >> 6;     // 0..7; wv<4 -> Ps cols, wv>=4 -> Pd cols
    const int lrow = lane & 15;
    const int lkg = lane >> 4;

    f32x4 acc[4][4];
#pragma unroll
    for (int mi = 0; mi < 4; ++mi)
#pragma unroll
        for (int ni = 0; ni < 4; ++ni) acc[mi][ni] = (f32x4){0.f, 0.f, 0.f, 0.f};

    const short* xbase = &A[lrow][lkg * 8];
    const short* wbase = pW + (size_t)(wv * 64 + lrow) * WK + lkg * 8;

#pragma unroll
    for (int kt = 0; kt < 4; ++kt) {
        bf16x8 a[4], b[4];
#pragma unroll
        for (int mi = 0; mi < 4; ++mi)
            a[mi] = *(const bf16x8*)(xbase + mi * 16 * WK + kt * 32);
#pragma unroll
        for (int ni = 0; ni < 4; ++ni)
            b[ni] = *(const bf16x8*)(wbase + ni * 16 * WK + kt * 32);
#pragma unroll
        for (int mi = 0; mi < 4; ++mi)
#pragma unroll
            for (int ni = 0; ni < 4; ++ni)
                acc[mi][ni] = __builtin_amdgcn_mfma_f32_16x16x32_bf16(a[mi], b[ni], acc[mi][ni], 0, 0, 0);
    }

    const int cb = (wv & 3) * 64;
    if (wv < 4) {
#pragma unroll
        for (int mi = 0; mi < 4; ++mi)
#pragma unroll
            for (int reg = 0; reg < 4; ++reg) {
                int node = n0 + mi * 16 + lkg * 4 + reg;
                int w = __builtin_amdgcn_cvt_pk_fp8_f32(acc[mi][0][reg], acc[mi][1][reg], 0, false);
                w = __builtin_amdgcn_cvt_pk_fp8_f32(acc[mi][2][reg], acc[mi][3][reg], w, true);
                if (node < NNODE)
                    *(unsigned*)(Ps8 + (size_t)node * 256 + cb + lrow * 4) = (unsigned)w;
            }
    } else {
#pragma unroll
        for (int mi = 0; mi < 4; ++mi)
#pragma unroll
            for (int reg = 0; reg < 4; ++reg) {
                int node = n0 + mi * 16 + lkg * 4 + reg;
                bf16x4 t;
                t[0] = f2bf(acc[mi][0][reg]);
                t[1] = f2bf(acc[mi][1][reg]);
                t[2] = f2bf(acc[mi][2][reg]);
                t[3] = f2bf(acc[mi][3][reg]);
                if (node < NNODE)
                    *(bf16x4*)(Pd + (size_t)node * 256 + cb + lrow * 4) = t;
            }
    }
}

// ---------------- fused edge-gate + aggregate: one wave per dst node ----------------
// Round-12 math, 2-deep straight-line software pipeline (loop-carried regs,
// unconditional prefetch against 4 sentinel records).
__global__ __launch_bounds__(256)
void edge_agg(const unsigned char* __restrict__ Ps8, const short* __restrict__ Pd,
              const unsigned char* __restrict__ h8,
              const int2* __restrict__ epk, const int* __restrict__ rowptr,
              const float* __restrict__ w1a_p, const float* __restrict__ b1_p,
              const float* __restrict__ w2_p, const float* __restrict__ b2,
              const float* __restrict__ luts,
              short* __restrict__ u2)          // aliases Pd: row stride 256, first 128 cols
{
    __shared__ float sg[LUTN];   // gelu table
    __shared__ float ss[LUTN];   // sigmoid table

    const int tid = threadIdx.x;
#pragma unroll
    for (int i = 0; i < LUTN / 256; ++i) {
        sg[tid + i * 256] = luts[tid + i * 256];
        ss[tid + i * 256] = luts[LUTN + tid + i * 256];
    }
    __syncthreads();

    const int node = (blockIdx.x * 256 + tid) >> 6;
    const int lane = tid & 63;

    const int beg = __builtin_amdgcn_readfirstlane(rowptr[node]);
    const int end = __builtin_amdgcn_readfirstlane(rowptr[node + 1]);
    const int d = end - beg;

    const float4 w1av = ((const float4*)w1a_p)[lane];
    const float4 b1v  = ((const float4*)b1_p)[lane];
    const float4 w2v  = ((const float4*)w2_p)[lane];
    const float b2s = b2[0];

    bf16x4 pd = *(const bf16x4*)(Pd + (size_t)node * 256 + lane * 4);
    const float pb0 = bf2f(pd[0]) + b1v.x;
    const float pb1 = bf2f(pd[1]) + b1v.y;
    const float pb2 = bf2f(pd[2]) + b1v.z;
    const float pb3 = bf2f(pd[3]) + b1v.w;

    const int2* ep = epk + beg;
    const unsigned pso = (unsigned)(lane * 4);   // bytes within fp8 Ps row
    const unsigned hvo = (unsigned)(lane * 2);   // bytes within fp8 h row

    float ax = 0.f, ay = 0.f, den = 0.f;

    if (d > 0) {
        // preload stages A (t=0) and B (t=1); reads past end hit sentinels/neighbors (valid)
        int2 sa0 = ep[0];
        int sA = __builtin_amdgcn_readfirstlane(sa0.x);
        float aA = __int_as_float(__builtin_amdgcn_readfirstlane(sa0.y));
        unsigned psA = *(const unsigned*)(Ps8 + (((size_t)(unsigned)sA) << 8) + pso);
        unsigned hvA = (unsigned)*(const unsigned short*)(h8 + (((size_t)(unsigned)sA) << 7) + hvo);

        int2 sa1 = ep[1];
        int sB = __builtin_amdgcn_readfirstlane(sa1.x);
        float aB = __int_as_float(__builtin_amdgcn_readfirstlane(sa1.y));
        unsigned psB = *(const unsigned*)(Ps8 + (((size_t)(unsigned)sB) << 8) + pso);
        unsigned hvB = (unsigned)*(const unsigned short*)(h8 + (((size_t)(unsigned)sB) << 7) + hvo);

        for (int t = 0; t < d; ++t) {
            // unconditional prefetch of stage C (t+2)
            int2 sa2 = ep[t + 2];
            int sC = __builtin_amdgcn_readfirstlane(sa2.x);
            float aC = __int_as_float(__builtin_amdgcn_readfirstlane(sa2.y));
            unsigned psC = *(const unsigned*)(Ps8 + (((size_t)(unsigned)sC) << 8) + pso);
            unsigned hvC = (unsigned)*(const unsigned short*)(h8 + (((size_t)(unsigned)sC) << 7) + hvo);

            // compute on stage A
            f32x2 plo = __builtin_amdgcn_cvt_pk_f32_fp8((int)psA, false);
            f32x2 phi = __builtin_amdgcn_cvt_pk_f32_fp8((int)psA, true);
            float x0 = plo[0] + pb0 + aA * w1av.x;
            float x1 = plo[1] + pb1 + aA * w1av.y;
            float x2 = phi[0] + pb2 + aA * w1av.z;
            float x3 = phi[1] + pb3 + aA * w1av.w;
            float p = lut_look(sg, x0) * w2v.x + lut_look(sg, x1) * w2v.y +
                      lut_look(sg, x2) * w2v.z + lut_look(sg, x3) * w2v.w;
            p += __shfl_xor(p, 1);
            p += __shfl_xor(p, 2);
            p += __shfl_xor(p, 4);
            p += __shfl_xor(p, 8);
            p += __shfl_xor(p, 16);
            p += __shfl_xor(p, 32);
            float g = lut_look(ss, p + b2s);
            f32x2 hxy = __builtin_amdgcn_cvt_pk_f32_fp8((int)hvA, false);
            ax = fmaf(g, hxy[0], ax);
            ay = fmaf(g, hxy[1], ay);
            den += g;

            // rotate pipeline
            psA = psB; hvA = hvB; aA = aB;
            psB = psC; hvB = hvC; aB = aC;
        }
    }

    float dd = fmaxf(den, 1e-6f);
    float dinv = __builtin_amdgcn_rcpf(dd);
    dinv = dinv * (2.0f - dd * dinv);
    unsigned pk = (((unsigned)(unsigned short)f2bf(ay * dinv)) << 16) |
                  (unsigned)(unsigned short)f2bf(ax * dinv);
    *(unsigned*)(u2 + (size_t)node * 256 + lane * 2) = pk;
}

// ---------------- node MLP: 64 nodes/block, SINGLE LDS buffer (U -> G -> R) ----------------
__global__ __launch_bounds__(256, 4)
void node_mlp(const float* __restrict__ hin,   // f32 residual
              const short* __restrict__ hb,    // bf16
              const short* __restrict__ u2,    // bf16 agg, row stride 256
              const short* __restrict__ W1T,   // [256][WLD]
              const float* __restrict__ b1,
              const short* __restrict__ W2T,   // [128][WLD]
              const float* __restrict__ b2,
              const float* __restrict__ lng, const float* __restrict__ lnb,
              float* __restrict__ hout, short* __restrict__ hb_out,
              unsigned char* __restrict__ h8_out)
{
    __shared__ short U[64][WLD];   // 33792 B: staged U, then G (gelu), then R (f32 overlay)

    const int tid = threadIdx.x;
    const int n0 = blockIdx.x * 64;
    const int lane = tid & 63;
    const int wv = tid >> 6;

    for (int idx = tid; idx < 64 * 32; idx += 256) {
        int nl = idx >> 5, q = idx & 31;
        int gn = min(n0 + nl, NNODE - 1);
        const short* src = (q < 16) ? (hb + (size_t)gn * DIM + q * 8)
                                    : (u2 + (size_t)gn * 256 + (q - 16) * 8);
        *(bf16x8*)&U[nl][q * 8] = *(const bf16x8*)src;
    }
    __syncthreads();

    const int lrow = lane & 15;
    const int lkg = lane >> 4;
    const int n0w = wv * 64;

    // GEMM1: [64][256] x [256][256], acc in regs
    f32x4 acc1[4][4];
#pragma unroll
    for (int mi = 0; mi < 4; ++mi)
#pragma unroll
        for (int ni = 0; ni < 4; ++ni) acc1[mi][ni] = (f32x4){0.f, 0.f, 0.f, 0.f};
    {
        const short* xbase = &U[lrow][lkg * 8];
        const short* wbase = W1T + (size_t)(n0w + lrow) * WLD + lkg * 8;
#pragma unroll
        for (int kt = 0; kt < 8; ++kt) {
            bf16x8 a[4], b[4];
#pragma unroll
            for (int mi = 0; mi < 4; ++mi)
                a[mi] = *(const bf16x8*)(xbase + mi * 16 * WLD + kt * 32);
#pragma unroll
            for (int ni = 0; ni < 4; ++ni)
                b[ni] = *(const bf16x8*)(wbase + ni * 16 * WLD + kt * 32);
#pragma unroll
            for (int mi = 0; mi < 4; ++mi)
#pragma unroll
                for (int ni = 0; ni < 4; ++ni)
                    acc1[mi][ni] = __builtin_amdgcn_mfma_f32_16x16x32_bf16(a[mi], b[ni], acc1[mi][ni], 0, 0, 0);
        }
    }
    __syncthreads();   // all U reads complete before overwrite

    // write G = gelu(acc1 + b1) over the same buffer
    {
        float b1v[4];
#pragma unroll
        for (int ni = 0; ni < 4; ++ni) b1v[ni] = b1[n0w + ni * 16 + lrow];
#pragma unroll
        for (int mi = 0; mi < 4; ++mi)
#pragma unroll
            for (int ni = 0; ni < 4; ++ni)
#pragma unroll
                for (int reg = 0; reg < 4; ++reg) {
                    int row = mi * 16 + lkg * 4 + reg;
                    int col = n0w + ni * 16 + lrow;
                    U[row][col] = f2bf(gelu_erf(acc1[mi][ni][reg] + b1v[ni]));
                }
    }
    __syncthreads();

    // GEMM2: [64][256] x [256][128], acc in regs (buffer still holds G)
    f32x4 acc2[4][2];
#pragma unroll
    for (int mi = 0; mi < 4; ++mi)
#pragma unroll
        for (int ni = 0; ni < 2; ++ni) acc2[mi][ni] = (f32x4){0.f, 0.f, 0.f, 0.f};
    {
        const short* xbase = &U[lrow][lkg * 8];
        const short* wbase = W2T + (size_t)(wv * 32 + lrow) * WLD + lkg * 8;
#pragma unroll
        for (int kt = 0; kt < 8; ++kt) {
            bf16x8 a[4], b[2];
#pragma unroll
            for (int mi = 0; mi < 4; ++mi)
                a[mi] = *(const bf16x8*)(xbase + mi * 16 * WLD + kt * 32);
#pragma unroll
            for (int ni = 0; ni < 2; ++ni)
                b[ni] = *(const bf16x8*)(wbase + ni * 16 * WLD + kt * 32);
#pragma unroll
            for (int mi = 0; mi < 4; ++mi)
#pragma unroll
                for (int ni = 0; ni < 2; ++ni)
                    acc2[mi][ni] = __builtin_amdgcn_mfma_f32_16x16x32_bf16(a[mi], b[ni], acc2[mi][ni], 0, 0, 0);
        }
    }
    __syncthreads();   // all G reads complete before R overlay

    // R f32 overlay [64][132] over the same buffer
    float* R = (float*)&U[0][0];
    {
        float b2v[2];
#pragma unroll
        for (int ni = 0; ni < 2; ++ni) b2v[ni] = b2[wv * 32 + ni * 16 + lrow];
#pragma unroll
        for (int mi = 0; mi < 4; ++mi)
#pragma unroll
            for (int ni = 0; ni < 2; ++ni)
#pragma unroll
                for (int reg = 0; reg < 4; ++reg) {
                    int row = mi * 16 + lkg * 4 + reg;
                    int col = wv * 32 + ni * 16 + lrow;
                    R[row * 132 + col] = acc2[mi][ni][reg] + b2v[ni];
                }
    }
    __syncthreads();

    // residual + LayerNorm; write hout f32 + hb bf16 + h8 fp8
#pragma unroll
    for (int ii = 0; ii < 16; ++ii) {
        int nl = wv * 16 + ii;
        int gn = n0 + nl;
        int gnc = min(gn, NNODE - 1);
        float rx = R[nl * 132 + lane * 2 + 0];
        float ry = R[nl * 132 + lane * 2 + 1];
        const float2 hh = *(const float2*)(hin + (size_t)gnc * DIM + lane * 2);
        float vx = rx + hh.x, vy = ry + hh.y;
        float s = vx + vy;
#pragma unroll
        for (int off = 32; off > 0; off >>= 1) s += __shfl_xor(s, off);
        float mu = s * (1.0f / 128.0f);
        float dx = vx - mu, dy = vy - mu;
        float q = dx * dx + dy * dy;
#pragma unroll
        for (int off = 32; off > 0; off >>= 1) q += __shfl_xor(q, off);
        float inv = rsqrtf(q * (1.0f / 128.0f) + 1e-5f);
        if (gn < NNODE) {
            const float2 gg = *(const float2*)(lng + lane * 2);
            const float2 bb = *(const float2*)(lnb + lane * 2);
            float ox = dx * inv * gg.x + bb.x;
            float oy = dy * inv * gg.y + bb.y;
            *(float2*)(hout + (size_t)gn * DIM + lane * 2) = make_float2(ox, oy);
            unsigned pk = ((unsigned)(unsigned short)f2bf(oy) << 16) |
                          (unsigned)(unsigned short)f2bf(ox);
            *(unsigned*)(hb_out + (size_t)gn * DIM + lane * 2) = pk;
            int w8 = __builtin_amdgcn_cvt_pk_fp8_f32(ox, oy, 0, false);
            *(unsigned short*)(h8_out + (size_t)gn * DIM + lane * 2) = (unsigned short)(w8 & 0xFFFF);
        }
    }
}

extern "C" void kernel_launch(void* const* d_in, const int* in_sizes, int n_in,
                              void* d_out, int out_size, void* d_ws, size_t ws_size,
                              hipStream_t stream) {
    const float* h0   = (const float*)d_in[0];
    const int*   ei   = (const int*)d_in[1];
    const float* attr = (const float*)d_in[2];
    const float* ew1  = (const float*)d_in[3];
    const float* eb1  = (const float*)d_in[4];
    const float* ew2  = (const float*)d_in[5];
    const float* eb2  = (const float*)d_in[6];
    const float* nw1  = (const float*)d_in[7];
    const float* nb1  = (const float*)d_in[8];
    const float* nw2  = (const float*)d_in[9];
    const float* nb2  = (const float*)d_in[10];
    const float* lng  = (const float*)d_in[11];
    const float* lnb  = (const float*)d_in[12];

    float* hout = (float*)d_out;

    char* p = (char*)d_ws;
    int*   rowptr = (int*)p;               p += sizeof(int) * (NNODE + 4);
    int*   cursor = (int*)p;               p += sizeof(int) * (NNODE + 4);
    int*   deg    = (int*)p;               p += sizeof(int) * (NNODE + 4);
    int*   bsum   = (int*)p;               p += sizeof(int) * 64;
    int2*  epk    = (int2*)p;              p += sizeof(int2) * (NEDGE + 4);
    short* hb     = (short*)p;             p += sizeof(short) * (size_t)NNODE * DIM;
    unsigned char* h8 = (unsigned char*)p; p += (size_t)NNODE * DIM;
    unsigned char* Ps8 = (unsigned char*)p; p += (size_t)NNODE * 256;
    short* Pd     = (short*)p;             p += sizeof(short) * (size_t)NNODE * 256;
    short* u2     = Pd;                    // alias: each wave reads only its own Pd row, then writes u2 there
    short* pW     = (short*)p;             p += sizeof(short) * (size_t)NLAYERS * 512 * WK;
    short* nW1T   = (short*)p;             p += sizeof(short) * (size_t)NLAYERS * 256 * WLD;
    short* nW2T   = (short*)p;             p += sizeof(short) * (size_t)NLAYERS * 128 * WLD;
    float* w1a_p  = (float*)p;             p += sizeof(float) * NLAYERS * 256;
    float* b1_p   = (float*)p;             p += sizeof(float) * NLAYERS * 256;
    float* w2_p   = (float*)p;             p += sizeof(float) * NLAYERS * 256;
    float* luts   = (float*)p;             p += sizeof(float) * 2 * LUTN;

    const int PREP_TOTAL = NLAYERS * 512 * 128 + NLAYERS * 256 * 256 +
                           NLAYERS * 128 * 256 + NLAYERS * 256 + NNODE * DIM / 8 +
                           2 * LUTN + NEDGE;

    hipMemsetAsync(deg, 0, (NNODE + 1) * sizeof(int), stream);
    prep_weights<<<(PREP_TOTAL + 255) / 256, 256, 0, stream>>>(
        ew1, eb1, ew2, nw1, nw2, h0, ei, pW, nW1T, nW2T, w1a_p, b1_p, w2_p, hb, h8, luts, deg);
    scan_part1<<<SCAN_BLOCKS, 1024, 0, stream>>>(deg, bsum);
    scan_part2<<<1, 64, 0, stream>>>(bsum, rowptr);
    scan_part3<<<SCAN_BLOCKS, 1024, 0, stream>>>(deg, bsum, rowptr, cursor);
    csr_scatter<<<(NEDGE + 255) / 256, 256, 0, stream>>>(ei, attr, cursor, epk);

    for (int L = 0; L < NLAYERS; ++L) {
        const float* hin = (L == 0) ? h0 : hout;
        proj_kernel<<<(NNODE + 63) / 64, 512, 0, stream>>>(
            hb, pW + (size_t)L * 512 * WK, Ps8, Pd);
        edge_agg<<<NNODE / 4, 256, 0, stream>>>(
            Ps8, Pd, h8, epk, rowptr,
            w1a_p + (size_t)L * 256, b1_p + (size_t)L * 256,
            w2_p + (size_t)L * 256, eb2 + L, luts, u2);
        node_mlp<<<(NNODE + 63) / 64, 256, 0, stream>>>(
            hin, hb, u2,
            nW1T + (size_t)L * 256 * WLD, nb1 + (size_t)L * 256,
            nW2T + (size_t)L * 128 * WLD, nb2 + (size_t)L * 128,
            lng + (size_t)L * DIM, lnb + (size_t)L * DIM,
            hout, hb, h8);
    }
}

// Round 16
// 472.924 us; speedup vs baseline: 1.3445x; 1.0816x over previous
//
#include <hip/hip_runtime.h>
#include <math.h>

#define NNODE 100000
#define NEDGE 600000
#define DIM 128
#define HID 256
#define NLAYERS 2

typedef short bf16x8 __attribute__((ext_vector_type(8)));
typedef short bf16x4 __attribute__((ext_vector_type(4)));
typedef float f32x4 __attribute__((ext_vector_type(4)));
typedef float f32x2 __attribute__((ext_vector_type(2)));

#define WK 136    // proj weight LD (k=128 + pad)
#define WLD 264   // node weight / LDS tile LD (k=256 + pad)
#define LUTN 2048 // entries per table, domain [-8,8), step 1/128
#define SCAN_CHUNK 4096
#define SCAN_BLOCKS ((NNODE + SCAN_CHUNK - 1) / SCAN_CHUNK)   // 25

__device__ __forceinline__ short f2bf(float x) {
    union { float f; unsigned u; } v; v.f = x;
    unsigned r = v.u + 0x7FFFu + ((v.u >> 16) & 1u);
    return (short)(r >> 16);
}
__device__ __forceinline__ float bf2f(short s) {
    union { unsigned u; float f; } v; v.u = ((unsigned)(unsigned short)s) << 16;
    return v.f;
}
// accurate gelu (A&S erf) for node MLP
__device__ __forceinline__ float gelu_erf(float x) {
    float z = x * 0.70710678118654752f;
    float az = fabsf(z);
    float t = __builtin_amdgcn_rcpf(1.0f + 0.3275911f * az);
    float y = t * (0.254829592f + t * (-0.284496736f + t * (1.421413741f +
              t * (-1.453152027f + t * 1.061405429f))));
    float e = __expf(-az * az);
    float er = 1.0f - y * e;
    er = copysignf(er, z);
    return 0.5f * x * (1.0f + er);
}
// LDS LUT lookup: value at nearest grid point of [-8,8) step 1/128
__device__ __forceinline__ float lut_look(const float* __restrict__ lut, float x) {
    float t = fmaf(x, 128.f, 1024.5f);
    t = fminf(fmaxf(t, 0.f), 2047.f);
    return lut[(int)t];
}

// ---------------- prep: weights -> bf16 transposed + permuted edge vectors + h0->bf16/fp8 + LUTs + deg hist ----------------
__global__ void prep_weights(const float* __restrict__ ew1,   // [L][257][256]
                             const float* __restrict__ eb1,   // [L][256]
                             const float* __restrict__ ew2,   // [L][256][1]
                             const float* __restrict__ nw1,   // [L][256][256]
                             const float* __restrict__ nw2,   // [L][256][128]
                             const float* __restrict__ h0,    // [N][128] f32
                             const int* __restrict__ ei,      // [E][2]
                             short* __restrict__ pW,          // [L][512][WK]
                             short* __restrict__ nW1T,        // [L][256][WLD]
                             short* __restrict__ nW2T,        // [L][128][WLD]
                             float* __restrict__ w1a_p,       // [L][256] permuted
                             float* __restrict__ b1_p,        // [L][256] permuted
                             float* __restrict__ w2_p,        // [L][256] permuted
                             short* __restrict__ hb,          // [N][128] bf16
                             unsigned char* __restrict__ h8,  // [N][128] fp8 e4m3
                             float* __restrict__ luts,        // [2*LUTN]: gelu | sigmoid
                             int* __restrict__ deg)
{
    int idx = blockIdx.x * 256 + threadIdx.x;
    const int SZ1 = NLAYERS * 512 * 128;
    const int SZ2 = NLAYERS * 256 * 256;
    const int SZ3 = NLAYERS * 128 * 256;
    const int SZ4 = NLAYERS * 256;
    const int SZH = NNODE * DIM / 8;
    if (idx < SZ1) {
        int L = idx / (512 * 128); int rr = idx - L * 512 * 128;
        int r = rr >> 7, k = rr & 127;
        int srow = (r < 256) ? k : 128 + k;
        int scol = (r < 256) ? r : r - 256;
        pW[(size_t)L * 512 * WK + r * WK + k] = f2bf(ew1[(size_t)L * 257 * 256 + srow * 256 + scol]);
        return;
    }
    idx -= SZ1;
    if (idx < SZ2) {
        int L = idx >> 16, r = idx & 65535, n = r >> 8, k = r & 255;
        nW1T[(size_t)L * 256 * WLD + n * WLD + k] = f2bf(nw1[(size_t)L * 256 * 256 + k * 256 + n]);
        return;
    }
    idx -= SZ2;
    if (idx < SZ3) {
        int L = idx >> 15, r = idx & 32767, n = r >> 8, k = r & 255;
        nW2T[(size_t)L * 128 * WLD + n * WLD + k] = f2bf(nw2[(size_t)L * 256 * 128 + k * 128 + n]);
        return;
    }
    idx -= SZ3;
    if (idx < SZ4) {
        int L = idx >> 8, c = idx & 255;
        int cs = (c & ~63) | ((c & 3) * 16 + ((c >> 2) & 15));
        w1a_p[idx] = ew1[(size_t)L * 257 * 256 + 256 * 256 + cs];
        b1_p[idx]  = eb1[(size_t)L * 256 + cs];
        w2_p[idx]  = ew2[(size_t)L * 256 + cs];
        return;
    }
    idx -= SZ4;
    if (idx < SZH) {
        const float4* p = (const float4*)(h0 + (size_t)idx * 8);
        float4 a = p[0], b = p[1];
        bf16x8 t;
        t[0] = f2bf(a.x); t[1] = f2bf(a.y); t[2] = f2bf(a.z); t[3] = f2bf(a.w);
        t[4] = f2bf(b.x); t[5] = f2bf(b.y); t[6] = f2bf(b.z); t[7] = f2bf(b.w);
        *(bf16x8*)(hb + (size_t)idx * 8) = t;
        int wa = __builtin_amdgcn_cvt_pk_fp8_f32(a.x, a.y, 0, false);
        wa = __builtin_amdgcn_cvt_pk_fp8_f32(a.z, a.w, wa, true);
        int wb = __builtin_amdgcn_cvt_pk_fp8_f32(b.x, b.y, 0, false);
        wb = __builtin_amdgcn_cvt_pk_fp8_f32(b.z, b.w, wb, true);
        *(unsigned*)(h8 + (size_t)idx * 8) = (unsigned)wa;
        *(unsigned*)(h8 + (size_t)idx * 8 + 4) = (unsigned)wb;
        return;
    }
    idx -= SZH;
    if (idx < 2 * LUTN) {
        int i = idx & (LUTN - 1);
        float x = (float)(i - 1024) * (1.0f / 128.0f);
        float v;
        if (idx < LUTN) {
            v = 0.5f * x * (1.0f + erff(x * 0.70710678118654752f));  // exact gelu
        } else {
            v = 1.0f / (1.0f + expf(-x));                            // exact sigmoid
        }
        luts[idx] = v;
        return;
    }
    idx -= 2 * LUTN;
    if (idx < NEDGE) {
        atomicAdd(&deg[ei[2 * idx + 1]], 1);
    }
}

// ---------------- CSR build: 3-phase parallel scan ----------------
__global__ __launch_bounds__(1024)
void scan_part1(const int* __restrict__ deg, int* __restrict__ bsum) {
    __shared__ int wsum[16];
    const int tid = threadIdx.x, lane = tid & 63, wv = tid >> 6;
    int i0 = blockIdx.x * SCAN_CHUNK + tid * 4;
    int v = 0;
    if (i0 + 3 < NNODE) {
        int4 q = *(const int4*)(deg + i0);
        v = q.x + q.y + q.z + q.w;
    } else if (i0 < NNODE) {
        v = deg[i0];
        if (i0 + 1 < NNODE) v += deg[i0 + 1];
        if (i0 + 2 < NNODE) v += deg[i0 + 2];
    }
#pragma unroll
    for (int off = 32; off > 0; off >>= 1) v += __shfl_xor(v, off);
    if (lane == 0) wsum[wv] = v;
    __syncthreads();
    if (tid == 0) {
        int s = 0;
#pragma unroll
        for (int w = 0; w < 16; ++w) s += wsum[w];
        bsum[blockIdx.x] = s;
    }
}

__global__ void scan_part2(int* __restrict__ bsum, int* __restrict__ rowptr) {
    const int lane = threadIdx.x;
    int v = (lane < SCAN_BLOCKS) ? bsum[lane] : 0;
    int x = v;
#pragma unroll
    for (int off = 1; off < 64; off <<= 1) {
        int y = __shfl_up(x, off);
        if (lane >= off) x += y;
    }
    if (lane < SCAN_BLOCKS) bsum[lane] = x - v;   // exclusive
    if (lane == 0) rowptr[NNODE] = NEDGE;
}

__global__ __launch_bounds__(1024)
void scan_part3(const int* __restrict__ deg, const int* __restrict__ bsum,
                int* __restrict__ rowptr, int* __restrict__ cursor) {
    __shared__ int wsum[16];
    const int tid = threadIdx.x, lane = tid & 63, wv = tid >> 6;
    int i0 = blockIdx.x * SCAN_CHUNK + tid * 4;
    int v0 = 0, v1 = 0, v2 = 0, v3 = 0;
    if (i0 + 3 < NNODE) {
        int4 q = *(const int4*)(deg + i0);
        v0 = q.x; v1 = q.y; v2 = q.z; v3 = q.w;
    } else if (i0 < NNODE) {
        v0 = deg[i0];
        if (i0 + 1 < NNODE) v1 = deg[i0 + 1];
        if (i0 + 2 < NNODE) v2 = deg[i0 + 2];
    }
    int tsum = v0 + v1 + v2 + v3;
    int x = tsum;
#pragma unroll
    for (int off = 1; off < 64; off <<= 1) {
        int y = __shfl_up(x, off);
        if (lane >= off) x += y;
    }
    if (lane == 63) wsum[wv] = x;
    __syncthreads();
    if (wv == 0) {
        int s = (lane < 16) ? wsum[lane] : 0;
#pragma unroll
        for (int off = 1; off < 16; off <<= 1) {
            int y = __shfl_up(s, off);
            if (lane >= off) s += y;
        }
        if (lane < 16) wsum[lane] = s;
    }
    __syncthreads();
    int carry = bsum[blockIdx.x];
    int woff = wv ? wsum[wv - 1] : 0;
    int e0 = carry + woff + (x - tsum);
    if (i0 < NNODE)     { rowptr[i0] = e0;           cursor[i0] = e0; }
    if (i0 + 1 < NNODE) { int v = e0 + v0;           rowptr[i0+1] = v; cursor[i0+1] = v; }
    if (i0 + 2 < NNODE) { int v = e0 + v0 + v1;      rowptr[i0+2] = v; cursor[i0+2] = v; }
    if (i0 + 3 < NNODE) { int v = e0 + v0 + v1 + v2; rowptr[i0+3] = v; cursor[i0+3] = v; }
}

__global__ void csr_scatter(const int* __restrict__ ei, const float* __restrict__ attr,
                            int* __restrict__ cursor, int2* __restrict__ epk) {
    int e = blockIdx.x * 256 + threadIdx.x;
    if (e >= NEDGE) return;
    int s = ei[2 * e], d = ei[2 * e + 1];
    int pos = atomicAdd(&cursor[d], 1);
    int2 pk; pk.x = s; pk.y = __float_as_int(attr[e]);
    epk[pos] = pk;
    if (e == 0) { int2 z; z.x = 0; z.y = 0; epk[NEDGE] = z; }  // sentinel for branch-free prefetch
}

// ---------------- proj: Ps(fp8) = h@W1s, Pd(bf16) = h@W1d (permuted column layout) ----------------
__global__ __launch_bounds__(512, 2)
void proj_kernel(const short* __restrict__ hb,    // [N][128] bf16
                 const short* __restrict__ pW,    // [512][WK]
                 unsigned char* __restrict__ Ps8, // [N][256] fp8 e4m3 (permuted cols)
                 short* __restrict__ Pd)          // [N][256] bf16 (permuted cols)
{
    __shared__ short A[64][WK];
    const int tid = threadIdx.x;
    const int n0 = blockIdx.x * 64;

    for (int idx = tid; idx < 64 * 16; idx += 512) {
        int nl = idx >> 4, q = idx & 15;
        int gn = min(n0 + nl, NNODE - 1);
        *(bf16x8*)&A[nl][q * 8] = *(const bf16x8*)(hb + (size_t)gn * DIM + q * 8);
    }
    __syncthreads();

    const int lane = tid & 63;
    const int wv = tid >> 6;     // 0..7; wv<4 -> Ps cols, wv>=4 -> Pd cols
    const int lrow = lane & 15;
    const int lkg = lane >> 4;

    f32x4 acc[4][4];
#pragma unroll
    for (int mi = 0; mi < 4; ++mi)
#pragma unroll
        for (int ni = 0; ni < 4; ++ni) acc[mi][ni] = (f32x4){0.f, 0.f, 0.f, 0.f};

    const short* xbase = &A[lrow][lkg * 8];
    const short* wbase = pW + (size_t)(wv * 64 + lrow) * WK + lkg * 8;

#pragma unroll
    for (int kt = 0; kt < 4; ++kt) {
        bf16x8 a[4], b[4];
#pragma unroll
        for (int mi = 0; mi < 4; ++mi)
            a[mi] = *(const bf16x8*)(xbase + mi * 16 * WK + kt * 32);
#pragma unroll
        for (int ni = 0; ni < 4; ++ni)
            b[ni] = *(const bf16x8*)(wbase + ni * 16 * WK + kt * 32);
#pragma unroll
        for (int mi = 0; mi < 4; ++mi)
#pragma unroll
            for (int ni = 0; ni < 4; ++ni)
                acc[mi][ni] = __builtin_amdgcn_mfma_f32_16x16x32_bf16(a[mi], b[ni], acc[mi][ni], 0, 0, 0);
    }

    const int cb = (wv & 3) * 64;
    if (wv < 4) {
#pragma unroll
        for (int mi = 0; mi < 4; ++mi)
#pragma unroll
            for (int reg = 0; reg < 4; ++reg) {
                int node = n0 + mi * 16 + lkg * 4 + reg;
                int w = __builtin_amdgcn_cvt_pk_fp8_f32(acc[mi][0][reg], acc[mi][1][reg], 0, false);
                w = __builtin_amdgcn_cvt_pk_fp8_f32(acc[mi][2][reg], acc[mi][3][reg], w, true);
                if (node < NNODE)
                    *(unsigned*)(Ps8 + (size_t)node * 256 + cb + lrow * 4) = (unsigned)w;
            }
    } else {
#pragma unroll
        for (int mi = 0; mi < 4; ++mi)
#pragma unroll
            for (int reg = 0; reg < 4; ++reg) {
                int node = n0 + mi * 16 + lkg * 4 + reg;
                bf16x4 t;
                t[0] = f2bf(acc[mi][0][reg]);
                t[1] = f2bf(acc[mi][1][reg]);
                t[2] = f2bf(acc[mi][2][reg]);
                t[3] = f2bf(acc[mi][3][reg]);
                if (node < NNODE)
                    *(bf16x4*)(Pd + (size_t)node * 256 + cb + lrow * 4) = t;
            }
    }
}

// ---------------- fused edge-gate + aggregate: one wave per dst node ----------------
// Round-12 proven form: fp8 Ps (4B/lane) + fp8 h (2B/lane) gathers, LUT
// activations, scalar int2 edge records, branch-free 1-ahead prefetch.
__global__ __launch_bounds__(256)
void edge_agg(const unsigned char* __restrict__ Ps8, const short* __restrict__ Pd,
              const unsigned char* __restrict__ h8,
              const int2* __restrict__ epk, const int* __restrict__ rowptr,
              const float* __restrict__ w1a_p, const float* __restrict__ b1_p,
              const float* __restrict__ w2_p, const float* __restrict__ b2,
              const float* __restrict__ luts,
              short* __restrict__ u2)          // aliases Pd: row stride 256, first 128 cols
{
    __shared__ float sg[LUTN];   // gelu table
    __shared__ float ss[LUTN];   // sigmoid table

    const int tid = threadIdx.x;
#pragma unroll
    for (int i = 0; i < LUTN / 256; ++i) {
        sg[tid + i * 256] = luts[tid + i * 256];
        ss[tid + i * 256] = luts[LUTN + tid + i * 256];
    }
    __syncthreads();

    const int node = (blockIdx.x * 256 + tid) >> 6;
    const int lane = tid & 63;

    const int beg = __builtin_amdgcn_readfirstlane(rowptr[node]);
    const int end = __builtin_amdgcn_readfirstlane(rowptr[node + 1]);
    const int d = end - beg;

    const float4 w1av = ((const float4*)w1a_p)[lane];
    const float4 b1v  = ((const float4*)b1_p)[lane];
    const float4 w2v  = ((const float4*)w2_p)[lane];
    const float b2s = b2[0];

    bf16x4 pd = *(const bf16x4*)(Pd + (size_t)node * 256 + lane * 4);
    const float pb0 = bf2f(pd[0]) + b1v.x;
    const float pb1 = bf2f(pd[1]) + b1v.y;
    const float pb2 = bf2f(pd[2]) + b1v.z;
    const float pb3 = bf2f(pd[3]) + b1v.w;

    const int2* ep = epk + beg;
    const int pso = lane * 4;   // bytes within fp8 Ps row
    const int hvo = lane * 2;   // bytes within fp8 h row

    float ax = 0.f, ay = 0.f, den = 0.f;

    unsigned ps_n = 0;
    unsigned short hv_n = 0;
    float a_n = 0.f;
    if (d > 0) {
        int2 sa = ep[0];
        int s0 = __builtin_amdgcn_readfirstlane(sa.x);
        a_n = __int_as_float(__builtin_amdgcn_readfirstlane(sa.y));
        ps_n = *(const unsigned*)(Ps8 + ((size_t)s0 << 8) + pso);
        hv_n = *(const unsigned short*)(h8 + ((size_t)s0 << 7) + hvo);
    }
    for (int t = 0; t < d; ++t) {
        unsigned psu = ps_n; unsigned short hv = hv_n; float a = a_n;
        {   // branch-free prefetch (sentinel entry keeps ep[t+1] always valid)
            int2 sa = ep[t + 1];
            int s2 = __builtin_amdgcn_readfirstlane(sa.x);
            a_n = __int_as_float(__builtin_amdgcn_readfirstlane(sa.y));
            ps_n = *(const unsigned*)(Ps8 + ((size_t)s2 << 8) + pso);
            hv_n = *(const unsigned short*)(h8 + ((size_t)s2 << 7) + hvo);
        }
        f32x2 plo = __builtin_amdgcn_cvt_pk_f32_fp8((int)psu, false);
        f32x2 phi = __builtin_amdgcn_cvt_pk_f32_fp8((int)psu, true);
        float x0 = plo[0] + pb0 + a * w1av.x;
        float x1 = plo[1] + pb1 + a * w1av.y;
        float x2 = phi[0] + pb2 + a * w1av.z;
        float x3 = phi[1] + pb3 + a * w1av.w;
        float p = lut_look(sg, x0) * w2v.x + lut_look(sg, x1) * w2v.y +
                  lut_look(sg, x2) * w2v.z + lut_look(sg, x3) * w2v.w;
        p += __shfl_xor(p, 1);
        p += __shfl_xor(p, 2);
        p += __shfl_xor(p, 4);
        p += __shfl_xor(p, 8);
        p += __shfl_xor(p, 16);
        p += __shfl_xor(p, 32);
        float g = lut_look(ss, p + b2s);
        f32x2 hxy = __builtin_amdgcn_cvt_pk_f32_fp8((int)(unsigned)hv, false);
        ax = fmaf(g, hxy[0], ax);
        ay = fmaf(g, hxy[1], ay);
        den += g;
    }

    float dd = fmaxf(den, 1e-6f);
    float dinv = __builtin_amdgcn_rcpf(dd);
    dinv = dinv * (2.0f - dd * dinv);
    unsigned pk = (((unsigned)(unsigned short)f2bf(ay * dinv)) << 16) |
                  (unsigned)(unsigned short)f2bf(ax * dinv);
    *(unsigned*)(u2 + (size_t)node * 256 + lane * 2) = pk;
}

// ---------------- node MLP: 64 nodes/block, SINGLE LDS buffer (U -> G -> R) ----------------
__global__ __launch_bounds__(256, 4)
void node_mlp(const float* __restrict__ hin,   // f32 residual
              const short* __restrict__ hb,    // bf16
              const short* __restrict__ u2,    // bf16 agg, row stride 256
              const short* __restrict__ W1T,   // [256][WLD]
              const float* __restrict__ b1,
              const short* __restrict__ W2T,   // [128][WLD]
              const float* __restrict__ b2,
              const float* __restrict__ lng, const float* __restrict__ lnb,
              float* __restrict__ hout, short* __restrict__ hb_out,
              unsigned char* __restrict__ h8_out)
{
    __shared__ short U[64][WLD];   // 33792 B: staged U, then G (gelu), then R (f32 overlay)

    const int tid = threadIdx.x;
    const int n0 = blockIdx.x * 64;
    const int lane = tid & 63;
    const int wv = tid >> 6;

    for (int idx = tid; idx < 64 * 32; idx += 256) {
        int nl = idx >> 5, q = idx & 31;
        int gn = min(n0 + nl, NNODE - 1);
        const short* src = (q < 16) ? (hb + (size_t)gn * DIM + q * 8)
                                    : (u2 + (size_t)gn * 256 + (q - 16) * 8);
        *(bf16x8*)&U[nl][q * 8] = *(const bf16x8*)src;
    }
    __syncthreads();

    const int lrow = lane & 15;
    const int lkg = lane >> 4;
    const int n0w = wv * 64;

    // GEMM1: [64][256] x [256][256], acc in regs
    f32x4 acc1[4][4];
#pragma unroll
    for (int mi = 0; mi < 4; ++mi)
#pragma unroll
        for (int ni = 0; ni < 4; ++ni) acc1[mi][ni] = (f32x4){0.f, 0.f, 0.f, 0.f};
    {
        const short* xbase = &U[lrow][lkg * 8];
        const short* wbase = W1T + (size_t)(n0w + lrow) * WLD + lkg * 8;
#pragma unroll
        for (int kt = 0; kt < 8; ++kt) {
            bf16x8 a[4], b[4];
#pragma unroll
            for (int mi = 0; mi < 4; ++mi)
                a[mi] = *(const bf16x8*)(xbase + mi * 16 * WLD + kt * 32);
#pragma unroll
            for (int ni = 0; ni < 4; ++ni)
                b[ni] = *(const bf16x8*)(wbase + ni * 16 * WLD + kt * 32);
#pragma unroll
            for (int mi = 0; mi < 4; ++mi)
#pragma unroll
                for (int ni = 0; ni < 4; ++ni)
                    acc1[mi][ni] = __builtin_amdgcn_mfma_f32_16x16x32_bf16(a[mi], b[ni], acc1[mi][ni], 0, 0, 0);
        }
    }
    __syncthreads();   // all U reads complete before overwrite

    // write G = gelu(acc1 + b1) over the same buffer
    {
        float b1v[4];
#pragma unroll
        for (int ni = 0; ni < 4; ++ni) b1v[ni] = b1[n0w + ni * 16 + lrow];
#pragma unroll
        for (int mi = 0; mi < 4; ++mi)
#pragma unroll
            for (int ni = 0; ni < 4; ++ni)
#pragma unroll
                for (int reg = 0; reg < 4; ++reg) {
                    int row = mi * 16 + lkg * 4 + reg;
                    int col = n0w + ni * 16 + lrow;
                    U[row][col] = f2bf(gelu_erf(acc1[mi][ni][reg] + b1v[ni]));
                }
    }
    __syncthreads();

    // GEMM2: [64][256] x [256][128], acc in regs (buffer still holds G)
    f32x4 acc2[4][2];
#pragma unroll
    for (int mi = 0; mi < 4; ++mi)
#pragma unroll
        for (int ni = 0; ni < 2; ++ni) acc2[mi][ni] = (f32x4){0.f, 0.f, 0.f, 0.f};
    {
        const short* xbase = &U[lrow][lkg * 8];
        const short* wbase = W2T + (size_t)(wv * 32 + lrow) * WLD + lkg * 8;
#pragma unroll
        for (int kt = 0; kt < 8; ++kt) {
            bf16x8 a[4], b[2];
#pragma unroll
            for (int mi = 0; mi < 4; ++mi)
                a[mi] = *(const bf16x8*)(xbase + mi * 16 * WLD + kt * 32);
#pragma unroll
            for (int ni = 0; ni < 2; ++ni)
                b[ni] = *(const bf16x8*)(wbase + ni * 16 * WLD + kt * 32);
#pragma unroll
            for (int mi = 0; mi < 4; ++mi)
#pragma unroll
                for (int ni = 0; ni < 2; ++ni)
                    acc2[mi][ni] = __builtin_amdgcn_mfma_f32_16x16x32_bf16(a[mi], b[ni], acc2[mi][ni], 0, 0, 0);
        }
    }
    __syncthreads();   // all G reads complete before R overlay

    // R f32 overlay [64][132] over the same buffer
    float* R = (float*)&U[0][0];
    {
        float b2v[2];
#pragma unroll
        for (int ni = 0; ni < 2; ++ni) b2v[ni] = b2[wv * 32 + ni * 16 + lrow];
#pragma unroll
        for (int mi = 0; mi < 4; ++mi)
#pragma unroll
            for (int ni = 0; ni < 2; ++ni)
#pragma unroll
                for (int reg = 0; reg < 4; ++reg) {
                    int row = mi * 16 + lkg * 4 + reg;
                    int col = wv * 32 + ni * 16 + lrow;
                    R[row * 132 + col] = acc2[mi][ni][reg] + b2v[ni];
                }
    }
    __syncthreads();

    // residual + LayerNorm; write hout f32 + hb bf16 + h8 fp8
#pragma unroll
    for (int ii = 0; ii < 16; ++ii) {
        int nl = wv * 16 + ii;
        int gn = n0 + nl;
        int gnc = min(gn, NNODE - 1);
        float rx = R[nl * 132 + lane * 2 + 0];
        float ry = R[nl * 132 + lane * 2 + 1];
        const float2 hh = *(const float2*)(hin + (size_t)gnc * DIM + lane * 2);
        float vx = rx + hh.x, vy = ry + hh.y;
        float s = vx + vy;
#pragma unroll
        for (int off = 32; off > 0; off >>= 1) s += __shfl_xor(s, off);
        float mu = s * (1.0f / 128.0f);
        float dx = vx - mu, dy = vy - mu;
        float q = dx * dx + dy * dy;
#pragma unroll
        for (int off = 32; off > 0; off >>= 1) q += __shfl_xor(q, off);
        float inv = rsqrtf(q * (1.0f / 128.0f) + 1e-5f);
        if (gn < NNODE) {
            const float2 gg = *(const float2*)(lng + lane * 2);
            const float2 bb = *(const float2*)(lnb + lane * 2);
            float ox = dx * inv * gg.x + bb.x;
            float oy = dy * inv * gg.y + bb.y;
            *(float2*)(hout + (size_t)gn * DIM + lane * 2) = make_float2(ox, oy);
            unsigned pk = ((unsigned)(unsigned short)f2bf(oy) << 16) |
                          (unsigned)(unsigned short)f2bf(ox);
            *(unsigned*)(hb_out + (size_t)gn * DIM + lane * 2) = pk;
            int w8 = __builtin_amdgcn_cvt_pk_fp8_f32(ox, oy, 0, false);
            *(unsigned short*)(h8_out + (size_t)gn * DIM + lane * 2) = (unsigned short)(w8 & 0xFFFF);
        }
    }
}

extern "C" void kernel_launch(void* const* d_in, const int* in_sizes, int n_in,
                              void* d_out, int out_size, void* d_ws, size_t ws_size,
                              hipStream_t stream) {
    const float* h0   = (const float*)d_in[0];
    const int*   ei   = (const int*)d_in[1];
    const float* attr = (const float*)d_in[2];
    const float* ew1  = (const float*)d_in[3];
    const float* eb1  = (const float*)d_in[4];
    const float* ew2  = (const float*)d_in[5];
    const float* eb2  = (const float*)d_in[6];
    const float* nw1  = (const float*)d_in[7];
    const float* nb1  = (const float*)d_in[8];
    const float* nw2  = (const float*)d_in[9];
    const float* nb2  = (const float*)d_in[10];
    const float* lng  = (const float*)d_in[11];
    const float* lnb  = (const float*)d_in[12];

    float* hout = (float*)d_out;

    char* p = (char*)d_ws;
    int*   rowptr = (int*)p;               p += sizeof(int) * (NNODE + 4);
    int*   cursor = (int*)p;               p += sizeof(int) * (NNODE + 4);
    int*   deg    = (int*)p;               p += sizeof(int) * (NNODE + 4);
    int*   bsum   = (int*)p;               p += sizeof(int) * 64;
    int2*  epk    = (int2*)p;              p += sizeof(int2) * (NEDGE + 4);
    short* hb     = (short*)p;             p += sizeof(short) * (size_t)NNODE * DIM;
    unsigned char* h8 = (unsigned char*)p; p += (size_t)NNODE * DIM;
    unsigned char* Ps8 = (unsigned char*)p; p += (size_t)NNODE * 256;
    short* Pd     = (short*)p;             p += sizeof(short) * (size_t)NNODE * 256;
    short* u2     = Pd;                    // alias: each wave reads only its own Pd row, then writes u2 there
    short* pW     = (short*)p;             p += sizeof(short) * (size_t)NLAYERS * 512 * WK;
    short* nW1T   = (short*)p;             p += sizeof(short) * (size_t)NLAYERS * 256 * WLD;
    short* nW2T   = (short*)p;             p += sizeof(short) * (size_t)NLAYERS * 128 * WLD;
    float* w1a_p  = (float*)p;             p += sizeof(float) * NLAYERS * 256;
    float* b1_p   = (float*)p;             p += sizeof(float) * NLAYERS * 256;
    float* w2_p   = (float*)p;             p += sizeof(float) * NLAYERS * 256;
    float* luts   = (float*)p;             p += sizeof(float) * 2 * LUTN;

    const int PREP_TOTAL = NLAYERS * 512 * 128 + NLAYERS * 256 * 256 +
                           NLAYERS * 128 * 256 + NLAYERS * 256 + NNODE * DIM / 8 +
                           2 * LUTN + NEDGE;

    hipMemsetAsync(deg, 0, (NNODE + 1) * sizeof(int), stream);
    prep_weights<<<(PREP_TOTAL + 255) / 256, 256, 0, stream>>>(
        ew1, eb1, ew2, nw1, nw2, h0, ei, pW, nW1T, nW2T, w1a_p, b1_p, w2_p, hb, h8, luts, deg);
    scan_part1<<<SCAN_BLOCKS, 1024, 0, stream>>>(deg, bsum);
    scan_part2<<<1, 64, 0, stream>>>(bsum, rowptr);
    scan_part3<<<SCAN_BLOCKS, 1024, 0, stream>>>(deg, bsum, rowptr, cursor);
    csr_scatter<<<(NEDGE + 255) / 256, 256, 0, stream>>>(ei, attr, cursor, epk);

    for (int L = 0; L < NLAYERS; ++L) {
        const float* hin = (L == 0) ? h0 : hout;
        proj_kernel<<<(NNODE + 63) / 64, 512, 0, stream>>>(
            hb, pW + (size_t)L * 512 * WK, Ps8, Pd);
        edge_agg<<<NNODE / 4, 256, 0, stream>>>(
            Ps8, Pd, h8, epk, rowptr,
            w1a_p + (size_t)L * 256, b1_p + (size_t)L * 256,
            w2_p + (size_t)L * 256, eb2 + L, luts, u2);
        node_mlp<<<(NNODE + 63) / 64, 256, 0, stream>>>(
            hin, hb, u2,
            nW1T + (size_t)L * 256 * WLD, nb1 + (size_t)L * 256,
            nW2T + (size_t)L * 128 * WLD, nb2 + (size_t)L * 128,
            lng + (size_t)L * DIM, lnb + (size_t)L * DIM,
            hout, hb, h8);
    }
}